// Round 17
// baseline (107.826 us; speedup 1.0000x reference)
//
#include <hip/hip_runtime.h>
#include <math.h>

#define NPIX   131072      // 8*128*128
#define CCH    256
#define HW     16384       // 128*128
#define BSTR   4194304     // 256*16384 (features b-stride)
#define NUMC   21
#define KC     5376        // 21*256
#define NREP   16

typedef __attribute__((ext_vector_type(8))) short bf16x8;   // 8 bf16 (4 VGPRs)
typedef __attribute__((ext_vector_type(4))) float f32x4;

static __device__ __forceinline__ uint f2bf(float x) {      // f32 -> bf16 bits, RTNE
    uint u = __builtin_bit_cast(uint, x);
    return (u + 0x7FFFu + ((u >> 16) & 1u)) >> 16;
}
static __device__ __forceinline__ uint ohv(int lbl, int cls, uint iv) {
    return (lbl == cls) ? iv : 0u;                          // onehot*invn as bf16 bits
}
static __device__ __forceinline__ float rsq_fast(float x) { // single v_rsq_f32
#if __has_builtin(__builtin_amdgcn_rsqf)
    return __builtin_amdgcn_rsqf(x);
#else
    return rsqrtf(x);
#endif
}

// ---------------- kernel 1: pseudo labels + per-class counts ----------------
__global__ __launch_bounds__(256) void k_labels(const int* __restrict__ labels,
                                                const float* __restrict__ outputs_old,
                                                int* __restrict__ lab,
                                                float* __restrict__ gcnt)
{
    __shared__ float cnt[NUMC];
    if (threadIdx.x < NUMC) cnt[threadIdx.x] = 0.f;
    __syncthreads();

    int p = blockIdx.x * 256 + threadIdx.x;
    int b = p >> 14;
    int rem = p & 16383;
    int h = rem >> 7;
    int w = rem & 127;
    int ld = labels[b * 262144 + (h * 4) * 512 + (w * 4)];
    int out = ld;
    if (ld == 0) {
        const float* oo = outputs_old + (size_t)b * BSTR + (size_t)(h * 4) * 512 + (w * 4);
        float v0 = oo[0];
        float best = (v0 < 0.7f) ? 0.0f : v0;
        int bi = 0;
        #pragma unroll
        for (int c = 1; c < 16; ++c) {
            float v = oo[(size_t)c * 262144];
            v = (v < 0.7f) ? 0.0f : v;
            if (v > best) { best = v; bi = c; }   // strict > == first-occurrence argmax
        }
        out = bi;
    }
    lab[p] = out;
    unsafeAtomicAdd(&cnt[out], 1.0f);
    __syncthreads();
    if (threadIdx.x < NUMC) unsafeAtomicAdd(&gcnt[threadIdx.x], cnt[threadIdx.x]);
}

// ------------- kernel 2: 1KB-page loads + MFMA per-class sums ---------------
// 512 blocks (256 px-units x 2 tensors); block = 512 px = 2 super-units.
// Wave-load = ONE FULL CHANNEL ROW (1KB contiguous, wave-uniform channel) ->
// tests the DRAM-page-efficiency theory (512B->1KB per page visit).
// ssq fully lane-local (zero shuffles). Tile [256ch][256px] bf16 (128KB),
// 512B rows, XOR-swizzled (write==read involution). 1 block/CU.
__global__ __launch_bounds__(256, 1) void k_msum(const float* __restrict__ fa,
                                                 const float* __restrict__ fo,
                                                 const int* __restrict__ lab,
                                                 float* __restrict__ partA,
                                                 float* __restrict__ partO)
{
    __shared__ ushort tileB[CCH * 256];   // 128 KB
    __shared__ float  ssqP[4][256];       // 4 KB
    __shared__ float  invnS[256];         // 1 KB
    __shared__ int    labS[512];          // 2 KB

    const int t = threadIdx.x;
    const int w = t >> 6, l = t & 63;
    const int isO = blockIdx.x & 1;
    const float* __restrict__ src = isO ? fo : fa;
    float* part = isO ? partO : partA;

    const int pbase = (blockIdx.x >> 1) * 512;
    const int img   = pbase >> 14;
    const int hw0   = pbase & 16383;
    const float* g  = src + (size_t)img * BSTR + hw0;

    labS[t]       = lab[pbase + t];
    labS[256 + t] = lab[pbase + 256 + t];

    f32x4 acc[2][4];
    #pragma unroll
    for (int m = 0; m < 2; ++m)
        #pragma unroll
        for (int n = 0; n < 4; ++n)
            acc[m][n] = (f32x4){0.f, 0.f, 0.f, 0.f};

#define SWZ(ch_) ((((ch_) & 15) << 4) ^ (((ch_) & 1) << 8))

// one instruction = one full channel row (wave-uniform ch, lane l: px 4l..4l+3)
#define ISSUE(B, su, b) do { \
    _Pragma("unroll") \
    for (int i_ = 0; i_ < 8; ++i_) \
        B[i_] = *(const float4*)(g + (size_t)(w * 64 + (b) * 8 + i_) * HW \
                                 + (su) * 256 + 4 * l); \
    } while (0)

// lane-local ssq accum + RTNE bf16 pack + swizzled LDS store (8B per row)
#define PROC(B, b) do { \
    _Pragma("unroll") \
    for (int i_ = 0; i_ < 8; ++i_) { \
        float4 v_ = B[i_]; \
        s4.x += v_.x * v_.x;  s4.y += v_.y * v_.y; \
        s4.z += v_.z * v_.z;  s4.w += v_.w * v_.w; \
        int ch_ = w * 64 + (b) * 8 + i_; \
        uint lo_ = f2bf(v_.x) | (f2bf(v_.y) << 16); \
        uint hi_ = f2bf(v_.z) | (f2bf(v_.w) << 16); \
        *(uint2*)((char*)tileB + ch_ * 512 + ((8 * l) ^ SWZ(ch_))) = \
            make_uint2(lo_, hi_); \
    } \
    } while (0)

#define KSTEP(su, ks) do { \
    float4 ivA_ = *(const float4*)&invnS[(ks) * 32 + (l >> 4) * 8]; \
    float4 ivB_ = *(const float4*)&invnS[(ks) * 32 + (l >> 4) * 8 + 4]; \
    uint iv0 = f2bf(ivA_.x), iv1 = f2bf(ivA_.y), iv2 = f2bf(ivA_.z), iv3 = f2bf(ivA_.w); \
    uint iv4 = f2bf(ivB_.x), iv5 = f2bf(ivB_.y), iv6 = f2bf(ivB_.z), iv7 = f2bf(ivB_.w); \
    int4 la_ = *(const int4*)&labS[(su) * 256 + (ks) * 32 + (l >> 4) * 8]; \
    int4 lb_ = *(const int4*)&labS[(su) * 256 + (ks) * 32 + (l >> 4) * 8 + 4]; \
    const int cls0_ = l & 15, cls1_ = 16 + (l & 15); \
    uint4 u0_, u1_; \
    u0_.x = ohv(la_.x, cls0_, iv0) | (ohv(la_.y, cls0_, iv1) << 16); \
    u0_.y = ohv(la_.z, cls0_, iv2) | (ohv(la_.w, cls0_, iv3) << 16); \
    u0_.z = ohv(lb_.x, cls0_, iv4) | (ohv(lb_.y, cls0_, iv5) << 16); \
    u0_.w = ohv(lb_.z, cls0_, iv6) | (ohv(lb_.w, cls0_, iv7) << 16); \
    u1_.x = ohv(la_.x, cls1_, iv0) | (ohv(la_.y, cls1_, iv1) << 16); \
    u1_.y = ohv(la_.z, cls1_, iv2) | (ohv(la_.w, cls1_, iv3) << 16); \
    u1_.z = ohv(lb_.x, cls1_, iv4) | (ohv(lb_.y, cls1_, iv5) << 16); \
    u1_.w = ohv(lb_.z, cls1_, iv6) | (ohv(lb_.w, cls1_, iv7) << 16); \
    bf16x8 A0_ = __builtin_bit_cast(bf16x8, u0_); \
    bf16x8 A1_ = __builtin_bit_cast(bf16x8, u1_); \
    _Pragma("unroll") \
    for (int n_ = 0; n_ < 4; ++n_) { \
        const int chrow_ = (w * 4 + n_) * 16 + (l & 15); \
        const bf16x8 B_ = *(const bf16x8*)((const char*)tileB + chrow_ * 512 \
                            + (((ks) * 64 + (l >> 4) * 16) ^ SWZ(chrow_))); \
        acc[0][n_] = __builtin_amdgcn_mfma_f32_16x16x32_bf16(A0_, B_, acc[0][n_], 0, 0, 0); \
        acc[1][n_] = __builtin_amdgcn_mfma_f32_16x16x32_bf16(A1_, B_, acc[1][n_], 0, 0, 0); \
    } \
    } while (0)

    float4 bufA[8], bufB[8];
    float4 s4 = {0.f, 0.f, 0.f, 0.f};

    // ---- SU1: stream 256 channels as 1KB rows (8 bursts, dbuf) ----
    ISSUE(bufA, 0, 0);  ISSUE(bufB, 0, 1);
    PROC(bufA, 0);  ISSUE(bufA, 0, 2);
    PROC(bufB, 1);  ISSUE(bufB, 0, 3);
    PROC(bufA, 2);  ISSUE(bufA, 0, 4);
    PROC(bufB, 3);  ISSUE(bufB, 0, 5);
    PROC(bufA, 4);  ISSUE(bufA, 0, 6);
    PROC(bufB, 5);  ISSUE(bufB, 0, 7);
    PROC(bufA, 6);
    PROC(bufB, 7);
    // prefetch SU2's first bursts: in flight across SU1's reduce+MFMA
    ISSUE(bufA, 1, 0);  ISSUE(bufB, 1, 1);

    *(float4*)&ssqP[w][l * 4] = s4;
    __syncthreads();                       // tile + ssqP ready
    invnS[t] = rsq_fast(fmaxf(ssqP[0][t] + ssqP[1][t] + ssqP[2][t] + ssqP[3][t],
                              1e-24f));
    __syncthreads();                       // invn ready
    KSTEP(0, 0); KSTEP(0, 1); KSTEP(0, 2); KSTEP(0, 3);
    KSTEP(0, 4); KSTEP(0, 5); KSTEP(0, 6); KSTEP(0, 7);
    __syncthreads();                       // tile + ssqP free

    // ---- SU2 ----
    s4 = (float4){0.f, 0.f, 0.f, 0.f};
    PROC(bufA, 0);  ISSUE(bufA, 1, 2);
    PROC(bufB, 1);  ISSUE(bufB, 1, 3);
    PROC(bufA, 2);  ISSUE(bufA, 1, 4);
    PROC(bufB, 3);  ISSUE(bufB, 1, 5);
    PROC(bufA, 4);  ISSUE(bufA, 1, 6);
    PROC(bufB, 5);  ISSUE(bufB, 1, 7);
    PROC(bufA, 6);
    PROC(bufB, 7);

    *(float4*)&ssqP[w][l * 4] = s4;
    __syncthreads();
    invnS[t] = rsq_fast(fmaxf(ssqP[0][t] + ssqP[1][t] + ssqP[2][t] + ssqP[3][t],
                              1e-24f));
    __syncthreads();
    KSTEP(1, 0); KSTEP(1, 1); KSTEP(1, 2); KSTEP(1, 3);
    KSTEP(1, 4); KSTEP(1, 5); KSTEP(1, 6); KSTEP(1, 7);

#undef ISSUE
#undef PROC
#undef KSTEP
#undef SWZ

    // --- epilogue: D[cls][ch] -> replica atomics (col=lane&15, row=(lane>>4)*4+r) ---
    const int rep = (blockIdx.x >> 1) & (NREP - 1);
    #pragma unroll
    for (int m = 0; m < 2; ++m)
        #pragma unroll
        for (int n = 0; n < 4; ++n) {
            const int col = (w * 4 + n) * 16 + (l & 15);
            #pragma unroll
            for (int r = 0; r < 4; ++r) {
                const int row = m * 16 + (l >> 4) * 4 + r;
                if (row < NUMC)
                    unsafeAtomicAdd(&part[rep * KC + row * 256 + col], acc[m][n][r]);
            }
        }
}

// -------- kernel 3: parallel rep-reduction (42 rows, 688 KB in parallel) -----
__global__ __launch_bounds__(256) void k_red(const float* __restrict__ partA,
                                             const float* __restrict__ partO,
                                             float* __restrict__ gsum)
{
    const int b = blockIdx.x, t = threadIdx.x;
    const float* part = (b < 21) ? partA : partO;
    const int cls = (b < 21) ? b : b - 21;
    float s = 0.f;
    #pragma unroll
    for (int r = 0; r < NREP; ++r) s += part[r * KC + cls * 256 + t];
    gsum[b * 256 + t] = s;
}

// ---------------- kernel 4: finalize (tiny, 43 KB in) ----------------
__global__ __launch_bounds__(256) void k_final2(const float* __restrict__ gsum,
                                                const float* __restrict__ gcnt,
                                                float* __restrict__ out)
{
    __shared__ float anc[NUMC * 260];
    __shared__ float con[NUMC * 260];
    __shared__ float adc[NUMC * 44];
    __shared__ float cntS[NUMC];
    __shared__ float rowloss[NUMC];
    __shared__ float rowvalid[NUMC];

    if (threadIdx.x < NUMC) cntS[threadIdx.x] = gcnt[threadIdx.x];
    __syncthreads();
    for (int i = threadIdx.x; i < KC; i += 256) {
        int k = i >> 8, c = i & 255;
        float cn = cntS[k];
        bool pr = cn > 0.f;
        float d = pr ? cn : 1.f;
        anc[k * 260 + c] = pr ? gsum[k * 256 + c] / d : 0.f;
        con[k * 260 + c] = pr ? gsum[(NUMC + k) * 256 + c] / d : 0.f;
    }
    __syncthreads();
    // adc[k][j] = dot(anc_k, contrast_j)/T,  contrast = [anc; con]
    for (int pair = threadIdx.x; pair < NUMC * 2 * NUMC; pair += 256) {
        int k = pair / (2 * NUMC);
        int j = pair % (2 * NUMC);
        const float* ar = anc + k * 260;
        const float* br = (j < NUMC) ? (anc + j * 260) : (con + (j - NUMC) * 260);
        float s = 0.f;
        for (int c = 0; c < CCH; c += 4) {
            float4 a4 = *(const float4*)(ar + c);
            float4 b4 = *(const float4*)(br + c);
            s += a4.x * b4.x + a4.y * b4.y + a4.z * b4.z + a4.w * b4.w;
        }
        adc[k * 44 + j] = s / 0.07f;
    }
    __syncthreads();
    if (threadIdx.x < NUMC) {
        int k = threadIdx.x;
        bool pr = cntS[k] > 0.f;
        float neg = 0.f;       // faithful to source — negatives use UNshifted logits
        float mx = -1e30f;
        for (int j = 0; j < 2 * NUMC; ++j) {
            int cj = (j < NUMC) ? j : (j - NUMC);
            bool cp = cntS[cj] > 0.f;
            float v = adc[k * 44 + j];
            if (cp) {
                if (v > mx) mx = v;
                if (j != k && j != NUMC + k) neg += expf(v);
            }
        }
        float sh = adc[k * 44 + NUMC + k] - mx;
        float rl = -(sh - logf(expf(sh) + neg));
        rowloss[k] = pr ? rl : 0.f;
        rowvalid[k] = pr ? 1.f : 0.f;
    }
    __syncthreads();
    if (threadIdx.x == 0) {
        float s = 0.f, v = 0.f;
        for (int kk = 0; kk < NUMC; ++kk) { s += rowloss[kk]; v += rowvalid[kk]; }
        out[0] = s / fmaxf(v, 1.f);
    }
}

// ---------------- launch ----------------
extern "C" void kernel_launch(void* const* d_in, const int* in_sizes, int n_in,
                              void* d_out, int out_size, void* d_ws, size_t ws_size,
                              hipStream_t stream) {
    const int*   labels      = (const int*)  d_in[0];
    const float* feats_old   = (const float*)d_in[1];
    const float* feats       = (const float*)d_in[2];
    const float* outputs_old = (const float*)d_in[3];
    // d_in[4] (outputs) and d_in[5] (prototypes) are unused by the reference math.

    float* ws    = (float*)d_ws;
    int*   lab   = (int*)ws;                   // [131072]
    float* partA = ws + 131072;                // [16*5376]
    float* partO = partA + NREP * KC;          // [16*5376]
    float* gcnt  = partO + NREP * KC;          // [21]
    float* gsum  = gcnt + 32;                  // [42*256]

    hipMemsetAsync(partA, 0, (size_t)(2 * NREP * KC + NUMC) * sizeof(float), stream);

    k_labels<<<NPIX / 256, 256, 0, stream>>>(labels, outputs_old, lab, gcnt);
    k_msum  <<<512, 256, 0, stream>>>(feats, feats_old, lab, partA, partO);
    k_red   <<<42, 256, 0, stream>>>(partA, partO, gsum);
    k_final2<<<1, 256, 0, stream>>>(gsum, gcnt, (float*)d_out);
}

// Round 18
// 98.371 us; speedup vs baseline: 1.0961x; 1.0961x over previous
//
#include <hip/hip_runtime.h>
#include <math.h>

#define NPIX   131072      // 8*128*128
#define CCH    256
#define HW     16384       // 128*128
#define BSTR   4194304     // 256*16384 (features b-stride)
#define NUMC   21
#define KC     5376        // 21*256
#define NREP   16

typedef __attribute__((ext_vector_type(8))) short bf16x8;   // 8 bf16 (4 VGPRs)
typedef __attribute__((ext_vector_type(4))) float f32x4;

static __device__ __forceinline__ uint f2bf(float x) {      // f32 -> bf16 bits, RTNE
    uint u = __builtin_bit_cast(uint, x);
    return (u + 0x7FFFu + ((u >> 16) & 1u)) >> 16;
}
static __device__ __forceinline__ uint ohv(int lbl, int cls, uint iv) {
    return (lbl == cls) ? iv : 0u;                          // onehot*invn as bf16 bits
}
static __device__ __forceinline__ float rsq_fast(float x) { // single v_rsq_f32
#if __has_builtin(__builtin_amdgcn_rsqf)
    return __builtin_amdgcn_rsqf(x);
#else
    return rsqrtf(x);
#endif
}
// pack hi16(x),hi16(y) -> one word (bf16 trunc pair)
static __device__ __forceinline__ uint bfpack_trunc(float x, float y) {
    return __builtin_amdgcn_perm(__builtin_bit_cast(uint, y),
                                 __builtin_bit_cast(uint, x), 0x07060302u);
}

// ---------------- kernel 1: pseudo labels + per-class counts ----------------
__global__ __launch_bounds__(256) void k_labels(const int* __restrict__ labels,
                                                const float* __restrict__ outputs_old,
                                                int* __restrict__ lab,
                                                float* __restrict__ gcnt)
{
    __shared__ float cnt[NUMC];
    if (threadIdx.x < NUMC) cnt[threadIdx.x] = 0.f;
    __syncthreads();

    int p = blockIdx.x * 256 + threadIdx.x;
    int b = p >> 14;
    int rem = p & 16383;
    int h = rem >> 7;
    int w = rem & 127;
    int ld = labels[b * 262144 + (h * 4) * 512 + (w * 4)];
    int out = ld;
    if (ld == 0) {
        const float* oo = outputs_old + (size_t)b * BSTR + (size_t)(h * 4) * 512 + (w * 4);
        float v0 = oo[0];
        float best = (v0 < 0.7f) ? 0.0f : v0;
        int bi = 0;
        #pragma unroll
        for (int c = 1; c < 16; ++c) {
            float v = oo[(size_t)c * 262144];
            v = (v < 0.7f) ? 0.0f : v;
            if (v > best) { best = v; bi = c; }   // strict > == first-occurrence argmax
        }
        out = bi;
    }
    lab[p] = out;
    unsafeAtomicAdd(&cnt[out], 1.0f);
    __syncthreads();
    if (threadIdx.x < NUMC) unsafeAtomicAdd(&gcnt[threadIdx.x], cnt[threadIdx.x]);
}

// ---------------- kernel 2: hw-contiguous stream + MFMA per-class sums -------
// Block = 256 px of one tensor (2 chunks x 128 px), 4 waves. Staging loads are
// CONTIGUOUS (wave-load = 2x512B segments). ssq lane-local. bf16 tile
// [256ch][128px] XOR-swizzled (write AND read, same involution).
// CHAMPION config: measured 96.5 us clean total (R10).
__global__ __launch_bounds__(256, 2) void k_msum(const float* __restrict__ fa,
                                                 const float* __restrict__ fo,
                                                 const int* __restrict__ lab,
                                                 float* __restrict__ partA,
                                                 float* __restrict__ partO)
{
    __shared__ ushort tileB[CCH * 128];   // 64 KB, row=ch (256B), XOR-swizzled
    __shared__ float  ssqP[4][128];       // per-wave ssq partials
    __shared__ float  invnS[128];
    __shared__ int    labS[256];

    const int t = threadIdx.x;
    const int w = t >> 6, l = t & 63;
    const int isO = blockIdx.x & 1;
    const float* __restrict__ src = isO ? fo : fa;
    float* part = isO ? partO : partA;

    const int pbase = (blockIdx.x >> 1) * 256;
    const int img   = pbase >> 14;
    const int hw0   = pbase & 16383;
    const float* g  = src + (size_t)img * BSTR + hw0;

    labS[t] = lab[pbase + t];

    f32x4 acc[2][4];
    #pragma unroll
    for (int m = 0; m < 2; ++m)
        #pragma unroll
        for (int n = 0; n < 4; ++n)
            acc[m][n] = (f32x4){0.f, 0.f, 0.f, 0.f};

#define LOADB(B, i0) do { \
    _Pragma("unroll") \
    for (int i_ = 0; i_ < 8; ++i_) \
        B[i_] = *(const float4*)(gc + (size_t)(w * 64 + 2 * ((i0) + i_) + (l >> 5)) * HW \
                                 + (l & 31) * 4); \
    } while (0)

#define PROCB(B, i0) do { \
    _Pragma("unroll") \
    for (int i_ = 0; i_ < 8; ++i_) { \
        float4 v_ = B[i_]; \
        s4.x += v_.x * v_.x;  s4.y += v_.y * v_.y; \
        s4.z += v_.z * v_.z;  s4.w += v_.w * v_.w; \
        int ch_ = w * 64 + 2 * ((i0) + i_) + (l >> 5); \
        uint lo_ = bfpack_trunc(v_.x, v_.y); \
        uint hi_ = bfpack_trunc(v_.z, v_.w); \
        *(uint2*)((char*)tileB + ch_ * 256 + ((((l & 31) * 8)) ^ ((ch_ & 7) << 4))) = \
            make_uint2(lo_, hi_); \
    } \
    } while (0)

#define KSTEP(c2, ks) do { \
    float4 ivA_ = *(const float4*)&invnS[(ks) * 32 + (l >> 4) * 8]; \
    float4 ivB_ = *(const float4*)&invnS[(ks) * 32 + (l >> 4) * 8 + 4]; \
    uint iv0 = f2bf(ivA_.x), iv1 = f2bf(ivA_.y), iv2 = f2bf(ivA_.z), iv3 = f2bf(ivA_.w); \
    uint iv4 = f2bf(ivB_.x), iv5 = f2bf(ivB_.y), iv6 = f2bf(ivB_.z), iv7 = f2bf(ivB_.w); \
    int4 la_ = *(const int4*)&labS[(c2) * 128 + (ks) * 32 + (l >> 4) * 8]; \
    int4 lb_ = *(const int4*)&labS[(c2) * 128 + (ks) * 32 + (l >> 4) * 8 + 4]; \
    const int cls0_ = l & 15, cls1_ = 16 + (l & 15); \
    uint4 u0_, u1_; \
    u0_.x = ohv(la_.x, cls0_, iv0) | (ohv(la_.y, cls0_, iv1) << 16); \
    u0_.y = ohv(la_.z, cls0_, iv2) | (ohv(la_.w, cls0_, iv3) << 16); \
    u0_.z = ohv(lb_.x, cls0_, iv4) | (ohv(lb_.y, cls0_, iv5) << 16); \
    u0_.w = ohv(lb_.z, cls0_, iv6) | (ohv(lb_.w, cls0_, iv7) << 16); \
    u1_.x = ohv(la_.x, cls1_, iv0) | (ohv(la_.y, cls1_, iv1) << 16); \
    u1_.y = ohv(la_.z, cls1_, iv2) | (ohv(la_.w, cls1_, iv3) << 16); \
    u1_.z = ohv(lb_.x, cls1_, iv4) | (ohv(lb_.y, cls1_, iv5) << 16); \
    u1_.w = ohv(lb_.z, cls1_, iv6) | (ohv(lb_.w, cls1_, iv7) << 16); \
    bf16x8 A0_ = __builtin_bit_cast(bf16x8, u0_); \
    bf16x8 A1_ = __builtin_bit_cast(bf16x8, u1_); \
    _Pragma("unroll") \
    for (int n_ = 0; n_ < 4; ++n_) { \
        const int chrow_ = (w * 4 + n_) * 16 + (l & 15); \
        const bf16x8 B_ = *(const bf16x8*)((const char*)tileB + chrow_ * 256 \
                            + (((ks) * 64 + (l >> 4) * 16) ^ ((chrow_ & 7) << 4))); \
        acc[0][n_] = __builtin_amdgcn_mfma_f32_16x16x32_bf16(A0_, B_, acc[0][n_], 0, 0, 0); \
        acc[1][n_] = __builtin_amdgcn_mfma_f32_16x16x32_bf16(A1_, B_, acc[1][n_], 0, 0, 0); \
    } \
    } while (0)

#define CHUNK(c2, LAST) do { \
    const float* gc = g + (c2) * 128; \
    float4 s4 = {0.f, 0.f, 0.f, 0.f}; \
    float4 bufA[8], bufB[8]; \
    LOADB(bufA, 0);  LOADB(bufB, 8); \
    PROCB(bufA, 0);  LOADB(bufA, 16); \
    PROCB(bufB, 8);  LOADB(bufB, 24); \
    PROCB(bufA, 16); PROCB(bufB, 24); \
    s4.x += __shfl_xor(s4.x, 32, 64);  s4.y += __shfl_xor(s4.y, 32, 64); \
    s4.z += __shfl_xor(s4.z, 32, 64);  s4.w += __shfl_xor(s4.w, 32, 64); \
    if (l < 32) *(float4*)&ssqP[w][l * 4] = s4; \
    __syncthreads(); \
    if (t < 128) { \
        float ss_ = ssqP[0][t] + ssqP[1][t] + ssqP[2][t] + ssqP[3][t]; \
        invnS[t] = rsq_fast(fmaxf(ss_, 1e-24f)); \
    } \
    __syncthreads(); \
    KSTEP(c2, 0); KSTEP(c2, 1); KSTEP(c2, 2); KSTEP(c2, 3); \
    if (!(LAST)) __syncthreads(); \
    } while (0)

    CHUNK(0, 0);
    CHUNK(1, 1);

#undef LOADB
#undef PROCB
#undef KSTEP
#undef CHUNK

    // --- epilogue: D[cls][ch] -> replica atomics (col=lane&15, row=(lane>>4)*4+r) ---
    const int rep = (blockIdx.x >> 1) & (NREP - 1);
    #pragma unroll
    for (int m = 0; m < 2; ++m)
        #pragma unroll
        for (int n = 0; n < 4; ++n) {
            const int col = (w * 4 + n) * 16 + (l & 15);
            #pragma unroll
            for (int r = 0; r < 4; ++r) {
                const int row = m * 16 + (l >> 4) * 4 + r;
                if (row < NUMC)
                    unsafeAtomicAdd(&part[rep * KC + row * 256 + col], acc[m][n][r]);
            }
        }
}

// ---------------- kernel 3: finalize (tiny) ----------------
__global__ __launch_bounds__(256) void k_final(const float* __restrict__ partA,
                                               const float* __restrict__ partO,
                                               const float* __restrict__ gcnt,
                                               float* __restrict__ out)
{
    __shared__ float anc[NUMC * 260];
    __shared__ float con[NUMC * 260];
    __shared__ float adc[NUMC * 44];
    __shared__ float cntS[NUMC];
    __shared__ float rowloss[NUMC];
    __shared__ float rowvalid[NUMC];

    if (threadIdx.x < NUMC) cntS[threadIdx.x] = gcnt[threadIdx.x];
    __syncthreads();
    for (int i = threadIdx.x; i < KC; i += 256) {
        float sA = 0.f, sO = 0.f;
        #pragma unroll
        for (int r = 0; r < NREP; ++r) { sA += partA[r * KC + i]; sO += partO[r * KC + i]; }
        int k = i >> 8, c = i & 255;
        float cn = cntS[k];
        bool pr = cn > 0.f;
        float d = pr ? cn : 1.f;
        anc[k * 260 + c] = pr ? sA / d : 0.f;
        con[k * 260 + c] = pr ? sO / d : 0.f;
    }
    __syncthreads();
    // adc[k][j] = dot(anc_k, contrast_j)/T,  contrast = [anc; con]
    for (int pair = threadIdx.x; pair < NUMC * 2 * NUMC; pair += 256) {
        int k = pair / (2 * NUMC);
        int j = pair % (2 * NUMC);
        const float* ar = anc + k * 260;
        const float* br = (j < NUMC) ? (anc + j * 260) : (con + (j - NUMC) * 260);
        float s = 0.f;
        for (int c = 0; c < CCH; c += 4) {
            float4 a4 = *(const float4*)(ar + c);
            float4 b4 = *(const float4*)(br + c);
            s += a4.x * b4.x + a4.y * b4.y + a4.z * b4.z + a4.w * b4.w;
        }
        adc[k * 44 + j] = s / 0.07f;
    }
    __syncthreads();
    if (threadIdx.x < NUMC) {
        int k = threadIdx.x;
        bool pr = cntS[k] > 0.f;
        float neg = 0.f;       // faithful to source — negatives use UNshifted logits
        float mx = -1e30f;
        for (int j = 0; j < 2 * NUMC; ++j) {
            int cj = (j < NUMC) ? j : (j - NUMC);
            bool cp = cntS[cj] > 0.f;
            float v = adc[k * 44 + j];
            if (cp) {
                if (v > mx) mx = v;
                if (j != k && j != NUMC + k) neg += expf(v);
            }
        }
        float sh = adc[k * 44 + NUMC + k] - mx;
        float rl = -(sh - logf(expf(sh) + neg));
        rowloss[k] = pr ? rl : 0.f;
        rowvalid[k] = pr ? 1.f : 0.f;
    }
    __syncthreads();
    if (threadIdx.x == 0) {
        float s = 0.f, v = 0.f;
        for (int kk = 0; kk < NUMC; ++kk) { s += rowloss[kk]; v += rowvalid[kk]; }
        out[0] = s / fmaxf(v, 1.f);
    }
}

// ---------------- launch ----------------
extern "C" void kernel_launch(void* const* d_in, const int* in_sizes, int n_in,
                              void* d_out, int out_size, void* d_ws, size_t ws_size,
                              hipStream_t stream) {
    const int*   labels      = (const int*)  d_in[0];
    const float* feats_old   = (const float*)d_in[1];
    const float* feats       = (const float*)d_in[2];
    const float* outputs_old = (const float*)d_in[3];
    // d_in[4] (outputs) and d_in[5] (prototypes) are unused by the reference math.

    float* ws    = (float*)d_ws;
    int*   lab   = (int*)ws;                   // [131072]
    float* partA = ws + 131072;                // [16*5376]
    float* partO = partA + NREP * KC;          // [16*5376]
    float* gcnt  = partO + NREP * KC;          // [21]

    hipMemsetAsync(partA, 0, (size_t)(2 * NREP * KC + NUMC) * sizeof(float), stream);

    k_labels<<<NPIX / 256, 256, 0, stream>>>(labels, outputs_old, lab, gcnt);
    k_msum  <<<1024, 256, 0, stream>>>(feats, feats_old, lab, partA, partO);
    k_final <<<1, 256, 0, stream>>>(partA, partO, gcnt, (float*)d_out);
}